// Round 8
// baseline (119.885 us; speedup 1.0000x reference)
//
#include <hip/hip_runtime.h>

// ---------------------------------------------------------------------------
// CrossGraphNodeAttention: out = softmax(mask(Q K^T / 16)) V per batch
//   Q = A@Wq^T+bq, K = B@Wk^T+bk, V = B@Wv^T+bv;  B=8, N=2048, H=256
// Round 8 (Design Z): 2-warp blocks, 4 independent blocks/CU, KVBLK=16 with
// 16x16x16 PV so P = cvt(sacc) stays in registers (C/D layout == x16
// B-operand layout for a 16x16 tile). bf16 Opart + bf16 combine. proj
// rebalanced to 768 x 64-row blocks with 32KB W quarters.
// ---------------------------------------------------------------------------

typedef __attribute__((ext_vector_type(8))) __bf16 bf16x8;
typedef __attribute__((ext_vector_type(4))) __bf16 bf16x4;
typedef __attribute__((ext_vector_type(4))) float f32x4;
typedef __attribute__((ext_vector_type(4))) short short4_t;

#if __has_builtin(__builtin_amdgcn_exp2f)
#define EXP2(x) __builtin_amdgcn_exp2f(x)
#else
#define EXP2(x) exp2f(x)
#endif

#define MFMA16(a, b, c) __builtin_amdgcn_mfma_f32_16x16x32_bf16((a), (b), (c), 0, 0, 0)

// 16x16x16 bf16 MFMA (A/B = 4 bf16 per lane). Builtin name varies by
// toolchain; guard three ways.
static __device__ __forceinline__ f32x4 pv_mfma(bf16x4 a, bf16x4 b, f32x4 c) {
#if __has_builtin(__builtin_amdgcn_mfma_f32_16x16x16_bf16)
  return __builtin_amdgcn_mfma_f32_16x16x16_bf16(a, b, c, 0, 0, 0);
#elif __has_builtin(__builtin_amdgcn_mfma_f32_16x16x16bf16_1k)
  return __builtin_amdgcn_mfma_f32_16x16x16bf16_1k(
      __builtin_bit_cast(short4_t, a), __builtin_bit_cast(short4_t, b), c, 0, 0, 0);
#else
  f32x4 d = c;
  asm volatile("v_mfma_f32_16x16x16_bf16 %0, %1, %2, %0"
               : "+v"(d)
               : "v"(a), "v"(b));
  return d;
#endif
}

typedef const __attribute__((address_space(1))) char gas_char;
typedef __attribute__((address_space(3))) char las_char;

static __device__ __forceinline__ void gload16(const void* g, void* l) {
  __builtin_amdgcn_global_load_lds((gas_char*)g, (las_char*)l, 16, 0, 0);
}

static __device__ __forceinline__ bf16x8 pack8(f32x4 a, f32x4 b) {
  bf16x8 r;
  r[0] = (__bf16)a[0]; r[1] = (__bf16)a[1]; r[2] = (__bf16)a[2]; r[3] = (__bf16)a[3];
  r[4] = (__bf16)b[0]; r[5] = (__bf16)b[1]; r[6] = (__bf16)b[2]; r[7] = (__bf16)b[3];
  return r;
}

// ---------------------------------------------------------------------------
__global__ void mask_kernel(const int* __restrict__ mask, float* __restrict__ mb) {
  int i = blockIdx.x * 256 + threadIdx.x;
  if (i < 8 * 2048) mb[i] = (mask[i] != 0) ? 0.0f : -1.0e30f;
}

// ---------------------------------------------------------------------------
// Projection: 768 blocks (3 proj x 256 row-groups of 64); 4 warps x 16 rows.
// W staged in 4 quarters of 32 KB (k-chunk XOR swizzle) -> 3 blocks/CU.
//  QF/KF fragment-major (x32 frags), verified r4-r7.
//  VF16 fragment-major for 16x16x16 A-operand:
//   idx = (n>>4)*4096 + (h>>4)*256 + (h&15)*4 + ((n>>2)&3)*64 + (n&3)
// ---------------------------------------------------------------------------
__global__ __launch_bounds__(256, 4) void proj_kernel(
    const float* __restrict__ A, const float* __restrict__ Bm,
    const float* __restrict__ Wq, const float* __restrict__ bq,
    const float* __restrict__ Wk, const float* __restrict__ bk,
    const float* __restrict__ Wv, const float* __restrict__ bv,
    __bf16* __restrict__ QF, __bf16* __restrict__ KF, __bf16* __restrict__ VF16) {
  __shared__ __bf16 Wl[256 * 64];  // 32 KB: quarter of W (k-quarter), swizzled
  const int pid = blockIdx.x;
  const int proj = pid >> 8;        // 0:Q 1:K 2:V
  const int rb = (pid & 255) << 6;  // row base in flattened [16384]
  const float* __restrict__ X = (proj == 0) ? A : Bm;
  const float* __restrict__ W = (proj == 0) ? Wq : (proj == 1 ? Wk : Wv);
  const float* __restrict__ bias = (proj == 0) ? bq : (proj == 1 ? bk : bv);
  const int tid = threadIdx.x;
  const int w = tid >> 6, l = tid & 63, lo = l & 15, g = l >> 4;
  const int r0 = rb + w * 16;

  f32x4 acc[16];
#pragma unroll
  for (int j = 0; j < 16; ++j) acc[j] = (f32x4){0.f, 0.f, 0.f, 0.f};

  for (int qtr = 0; qtr < 4; ++qtr) {
    if (qtr) __syncthreads();  // all warps done reading previous quarter
    for (int c = tid; c < 2048; c += 256) {
      int n = c >> 3;
      int k8 = (c & 7) << 3;
      const float* wp = &W[n * 256 + qtr * 64 + k8];
      f32x4 w0 = *(const f32x4*)wp;
      f32x4 w1 = *(const f32x4*)(wp + 4);
      int kx = k8 ^ ((n & 7) << 3);  // 8-elem-chunk XOR swizzle (within 64)
      *(bf16x8*)&Wl[n * 64 + kx] = pack8(w0, w1);
    }
    __syncthreads();
#pragma unroll
    for (int ks2 = 0; ks2 < 2; ++ks2) {
      const int kg = qtr * 64 + ks2 * 32 + g * 8;
      const float* xp = &X[(r0 + lo) * 256 + kg];
      bf16x8 xf = pack8(*(const f32x4*)xp, *(const f32x4*)(xp + 4));
#pragma unroll
      for (int nt = 0; nt < 16; ++nt) {
        int n = nt * 16 + lo;
        int kchunk = (ks2 * 4 + g) ^ (n & 7);
        bf16x8 wf = *(const bf16x8*)&Wl[n * 64 + kchunk * 8];
        if (proj == 2) {  // V: D = W * X^T -> V^T[h][row]
          acc[nt] = MFMA16(wf, xf, acc[nt]);
        } else {  // Q/K: D = X * W^T -> out[row][n]
          acc[nt] = MFMA16(xf, wf, acc[nt]);
        }
      }
    }
  }

  if (proj != 2) {
    const float cs = (proj == 0) ? 0.090168440f : 1.0f;  // log2(e)/16
    __bf16* __restrict__ O = (proj == 0) ? QF : KF;
    const size_t rgbase = (size_t)(r0 >> 4) << 12;
#pragma unroll
    for (int nt = 0; nt < 16; ++nt) {
      int h = nt * 16 + lo;
      float bb = bias[h];
      size_t hpart = (size_t)((h >> 5) << 9) + (((h >> 3) & 3) << 7) + (h & 7);
#pragma unroll
      for (int r = 0; r < 4; ++r) {
        int R = r0 + g * 4 + r;  // C-layout row
        O[rgbase + hpart + ((R & 15) << 3)] = (__bf16)((acc[nt][r] + bb) * cs);
      }
    }
  } else {
    const int bidx = r0 >> 11;
    const int nb = r0 & 2047;
    __bf16* __restrict__ Vo = VF16 + (size_t)bidx * 524288 +
                              ((size_t)(nb >> 4) << 12);
#pragma unroll
    for (int ht = 0; ht < 16; ++ht)
#pragma unroll
      for (int r = 0; r < 4; ++r) {
        int h = ht * 16 + g * 4 + r;  // C-layout row = h
        int n = nb + lo;              // C-layout col = kv
        Vo[((h >> 4) << 8) + ((h & 15) << 2) + (((n >> 2) & 3) << 6) + (n & 3)] =
            (__bf16)(acc[ht][r] + bias[h]);
      }
  }
}

// ---------------------------------------------------------------------------
// Attention: grid = 8 b x 32 qg x S; 2 warps x 32 q-rows (QBLK=64).
// KVBLK=16: K tile 8KB + V tile 8KB, double-buffered = 32 KB LDS ->
// 4 independent 2-warp blocks/CU (8 waves/CU). QK^T = x32 MFMA from LDS;
// P stays in registers (C/D==B-operand identity); PV = x16 MFMA.
// ---------------------------------------------------------------------------
__global__ __launch_bounds__(128, 2) void attn_kernel(
    const __bf16* __restrict__ QF, const __bf16* __restrict__ KF,
    const __bf16* __restrict__ VF16, const float* __restrict__ mb,
    __bf16* __restrict__ Opart, float* __restrict__ mpart,
    float* __restrict__ lpart, float* __restrict__ out,
    int chunk, int direct) {
  extern __shared__ char smem[];  // [K 2x8K][V 2x8K] = 32768 B
  const int bid = blockIdx.x;
  const int b = bid & 7;            // batch -> XCD pinning
  const int rest = bid >> 3;
  const int qg = rest & 31;
  const int s = rest >> 5;
  const int tid = threadIdx.x;
  const int w = tid >> 6, l = tid & 63, lo = l & 15, g = l >> 4;
  const int q0 = qg * 64 + w * 32;
  const __bf16* __restrict__ Qb = QF + ((size_t)b * 2048 + q0) * 256;
  const char* __restrict__ Kb = (const char*)(KF + (size_t)b * 2048 * 256);
  const char* __restrict__ Vb = (const char*)(VF16 + (size_t)b * 524288);
  const float* __restrict__ mbb = mb + b * 2048;

  bf16x8 qf[2][8];  // 2 q-row-tiles, x32 B-operand frags
#pragma unroll
  for (int u = 0; u < 2; ++u)
#pragma unroll
    for (int hs = 0; hs < 8; ++hs)
      qf[u][hs] = *(const bf16x8*)&Qb[u * 4096 + hs * 512 + l * 8];

  f32x4 oacc[2][16];
#pragma unroll
  for (int u = 0; u < 2; ++u)
#pragma unroll
    for (int i = 0; i < 16; ++i) oacc[u][i] = (f32x4){0.f, 0.f, 0.f, 0.f};
  float m[2] = {-3.0e28f, -3.0e28f}, lsum[2] = {0.f, 0.f};

  const int kv0 = s * chunk;
  const int niter = chunk >> 4;
  const int t0 = kv0 >> 4;

  // stage kv-16 tile t16 into buffer buf: each warp 4 K + 4 V gload16 (8KB).
  #define STAGE(t16, buf)                                                     \
    {                                                                         \
      const char* gk = Kb + (size_t)(t16) * 8192 + w * 4096 + l * 16;         \
      char* lk = smem + (buf)*8192 + w * 4096;                                \
      gload16(gk, lk);                                                        \
      gload16(gk + 1024, lk + 1024);                                          \
      gload16(gk + 2048, lk + 2048);                                          \
      gload16(gk + 3072, lk + 3072);                                          \
      const char* gv = Vb + (size_t)(t16) * 8192 + w * 4096 + l * 16;         \
      char* lv = smem + 16384 + (buf)*8192 + w * 4096;                        \
      gload16(gv, lv);                                                        \
      gload16(gv + 1024, lv + 1024);                                          \
      gload16(gv + 2048, lv + 2048);                                          \
      gload16(gv + 3072, lv + 3072);                                          \
    }

  STAGE(t0, 0);
  __syncthreads();  // tile 0 visible

  for (int it = 0; it < niter; ++it) {
    const int cur = it & 1;
    if (it + 1 < niter) STAGE(t0 + it + 1, cur ^ 1);  // prefetch other buf
    const char* kbase = smem + cur * 8192;
    const char* vbase = smem + 16384 + cur * 8192;

    // QK^T: S^T[16 kv][16 q] per u; each K frag feeds both q-tiles
    f32x4 sacc[2];
    sacc[0] = (f32x4){0.f, 0.f, 0.f, 0.f};
    sacc[1] = (f32x4){0.f, 0.f, 0.f, 0.f};
    __builtin_amdgcn_s_setprio(1);
#pragma unroll
    for (int hs = 0; hs < 8; ++hs) {
      bf16x8 kf = *(const bf16x8*)(kbase + hs * 1024 + l * 16);
      sacc[0] = MFMA16(kf, qf[0][hs], sacc[0]);
      sacc[1] = MFMA16(kf, qf[1][hs], sacc[1]);
    }
    __builtin_amdgcn_s_setprio(0);

    // mask bias + online softmax; P stays in registers (C/D == x16 B layout)
    const int kvb = kv0 + (it << 4);
    f32x4 bias4 = *(const f32x4*)&mbb[kvb + g * 4];
    bf16x4 pf[2];
#pragma unroll
    for (int u = 0; u < 2; ++u) {
      float tmax = -3.4e38f;
#pragma unroll
      for (int r = 0; r < 4; ++r) {
        sacc[u][r] += bias4[r];
        tmax = fmaxf(tmax, sacc[u][r]);
      }
      tmax = fmaxf(tmax, __shfl_xor(tmax, 16));
      tmax = fmaxf(tmax, __shfl_xor(tmax, 32));
      if (!__all(tmax <= m[u] + 8.0f)) {  // defer-max rescale
        float mn = fmaxf(m[u], tmax);
        float f = EXP2(m[u] - mn);
        lsum[u] *= f;
#pragma unroll
        for (int i = 0; i < 16; ++i) {
          oacc[u][i][0] *= f; oacc[u][i][1] *= f;
          oacc[u][i][2] *= f; oacc[u][i][3] *= f;
        }
        m[u] = mn;
      }
      float p0 = EXP2(sacc[u][0] - m[u]);
      float p1 = EXP2(sacc[u][1] - m[u]);
      float p2 = EXP2(sacc[u][2] - m[u]);
      float p3 = EXP2(sacc[u][3] - m[u]);
      lsum[u] += (p0 + p1) + (p2 + p3);
      pf[u][0] = (__bf16)p0; pf[u][1] = (__bf16)p1;
      pf[u][2] = (__bf16)p2; pf[u][3] = (__bf16)p3;
    }

    // PV: x16 MFMA; each V frag feeds both q-tiles
    __builtin_amdgcn_s_setprio(1);
#pragma unroll
    for (int ht = 0; ht < 16; ++ht) {
      bf16x4 vf = *(const bf16x4*)(vbase + ht * 512 + l * 8);
      oacc[0][ht] = pv_mfma(vf, pf[0], oacc[0][ht]);
      oacc[1][ht] = pv_mfma(vf, pf[1], oacc[1][ht]);
    }
    __builtin_amdgcn_s_setprio(0);
    __syncthreads();  // prefetch landed (vmcnt) + LDS reads done (lgkm)
  }

#pragma unroll
  for (int u = 0; u < 2; ++u) {
    float ls = lsum[u];
    ls += __shfl_xor(ls, 16);
    ls += __shfl_xor(ls, 32);
    const int q0u = q0 + u * 16;
    if (direct) {
      float inv = 1.0f / ls;
      float* __restrict__ Ob = out + ((size_t)b * 2048 + q0u) * 256;
#pragma unroll
      for (int ht = 0; ht < 16; ++ht) {
        f32x4 v = oacc[u][ht];
        v[0] *= inv; v[1] *= inv; v[2] *= inv; v[3] *= inv;
        *(f32x4*)&Ob[lo * 256 + ht * 16 + g * 4] = v;
      }
    } else {
      const size_t rowbase = (size_t)(s * 8 + b) * 2048 + q0u;
      __bf16* __restrict__ Ob = Opart + rowbase * 256;
#pragma unroll
      for (int ht = 0; ht < 16; ++ht) {
        f32x4 v = oacc[u][ht];
        bf16x4 pk;
        pk[0] = (__bf16)v[0]; pk[1] = (__bf16)v[1];
        pk[2] = (__bf16)v[2]; pk[3] = (__bf16)v[3];
        *(bf16x4*)&Ob[lo * 256 + ht * 16 + g * 4] = pk;
      }
      if (l < 16) {
        mpart[rowbase + lo] = m[u];
        lpart[rowbase + lo] = ls;
      }
    }
  }
}

// ---------------------------------------------------------------------------
// Combine: out[row][h] = sum_s 2^(m_s-M) O_s[row][h] / sum_s 2^(m_s-M) l_s
// Opart is bf16 (4 per thread = 8B coalesced loads).
// ---------------------------------------------------------------------------
__global__ __launch_bounds__(256) void combine_kernel(
    const __bf16* __restrict__ Opart, const float* __restrict__ mpart,
    const float* __restrict__ lpart, float* __restrict__ out, int nsplit) {
  int t = blockIdx.x * 256 + threadIdx.x;
  int row = t >> 6;
  int h4 = (t & 63) << 2;
  float M = -3.4e38f;
  for (int s = 0; s < nsplit; ++s) M = fmaxf(M, mpart[s * 16384 + row]);
  f32x4 acc = (f32x4){0.f, 0.f, 0.f, 0.f};
  float denom = 0.f;
  for (int s = 0; s < nsplit; ++s) {
    float wgt = EXP2(mpart[s * 16384 + row] - M);
    denom += wgt * lpart[s * 16384 + row];
    bf16x4 o = *(const bf16x4*)&Opart[((size_t)s * 16384 + row) * 256 + h4];
    acc[0] += wgt * (float)o[0]; acc[1] += wgt * (float)o[1];
    acc[2] += wgt * (float)o[2]; acc[3] += wgt * (float)o[3];
  }
  float inv = 1.0f / denom;
  f32x4 r;
  r[0] = acc[0] * inv; r[1] = acc[1] * inv;
  r[2] = acc[2] * inv; r[3] = acc[3] * inv;
  *(f32x4*)&out[(size_t)row * 256 + h4] = r;
}

// ---------------------------------------------------------------------------
extern "C" void kernel_launch(void* const* d_in, const int* in_sizes, int n_in,
                              void* d_out, int out_size, void* d_ws, size_t ws_size,
                              hipStream_t stream) {
  const float* A = (const float*)d_in[0];
  const float* B = (const float*)d_in[1];
  const int* mask = (const int*)d_in[2];
  const float* Wq = (const float*)d_in[3];
  const float* bq = (const float*)d_in[4];
  const float* Wk = (const float*)d_in[5];
  const float* bk = (const float*)d_in[6];
  const float* Wv = (const float*)d_in[7];
  const float* bv = (const float*)d_in[8];

  char* ws = (char*)d_ws;
  __bf16* QF = (__bf16*)(ws);                         // 8 MB
  __bf16* KF = (__bf16*)(ws + (8ull << 20));          // 8 MB
  __bf16* VF16 = (__bf16*)(ws + (16ull << 20));       // 8 MB
  float* mb = (float*)(ws + (24ull << 20));           // 64 KB
  float* mpart = (float*)(ws + (24ull << 20) + 0x10000);   // <=256 KB
  float* lpart = (float*)(ws + (24ull << 20) + 0x60000);   // <=256 KB
  __bf16* Opart = (__bf16*)(ws + (25ull << 20));           // S * 8 MB (bf16)

  const size_t base = 25ull << 20;
  const size_t part = 8ull << 20;
  int S;
  if (ws_size >= base + 4 * part) S = 4;
  else if (ws_size >= base + 2 * part) S = 2;
  else if (ws_size >= base + 1 * part) S = 1;
  else S = 0;  // direct mode (no split)

  const int SMEM = 32768;
  (void)hipFuncSetAttribute((const void*)attn_kernel,
                            hipFuncAttributeMaxDynamicSharedMemorySize, SMEM);

  mask_kernel<<<64, 256, 0, stream>>>(mask, mb);
  proj_kernel<<<768, 256, 0, stream>>>(A, B, Wq, bq, Wk, bk, Wv, bv, QF, KF, VF16);
  if (S == 0) {
    attn_kernel<<<256, 128, SMEM, stream>>>(QF, KF, VF16, mb, nullptr, nullptr,
                                            nullptr, (float*)d_out, 2048, 1);
  } else {
    attn_kernel<<<256 * S, 128, SMEM, stream>>>(QF, KF, VF16, mb, Opart, mpart,
                                                lpart, nullptr, 2048 / S, 0);
    combine_kernel<<<4096, 256, 0, stream>>>(Opart, mpart, lpart,
                                             (float*)d_out, S);
  }
}

// Round 9
// 102.722 us; speedup vs baseline: 1.1671x; 1.1671x over previous
//
#include <hip/hip_runtime.h>

// ---------------------------------------------------------------------------
// CrossGraphNodeAttention: out = softmax(mask(Q K^T / 16)) V per batch
//   Q = A@Wq^T+bq, K = B@Wk^T+bk, V = B@Wv^T+bv;  B=8, N=2048, H=256
// Round 9: r7 structure (QBLK=128, KVBLK=32, x32 MFMA, 2 blocks/CU) +
// T4 counted-vmcnt split-phase staging: K/V prefetch halves issued in
// separate phases, raw s_barrier preceded by s_waitcnt vmcnt(4) (never 0
// in the main loop) so prefetch stays in flight across barriers.
// Mask bias staged in LDS (no in-loop global loads -> vmcnt math exact).
// bf16 Opart + bf16 combine (r8 win). proj = 768 blocks, VF x32 layout.
// ---------------------------------------------------------------------------

typedef __attribute__((ext_vector_type(8))) __bf16 bf16x8;
typedef __attribute__((ext_vector_type(4))) __bf16 bf16x4;
typedef __attribute__((ext_vector_type(4))) float f32x4;

#if __has_builtin(__builtin_amdgcn_exp2f)
#define EXP2(x) __builtin_amdgcn_exp2f(x)
#else
#define EXP2(x) exp2f(x)
#endif

#define MFMA16(a, b, c) __builtin_amdgcn_mfma_f32_16x16x32_bf16((a), (b), (c), 0, 0, 0)

typedef const __attribute__((address_space(1))) char gas_char;
typedef __attribute__((address_space(3))) char las_char;

// global -> LDS direct copy: 16B/lane, LDS dest = uniform base (+lane*16 HW).
static __device__ __forceinline__ void gload16(const void* g, void* l) {
  __builtin_amdgcn_global_load_lds((gas_char*)g, (las_char*)l, 16, 0, 0);
}

static __device__ __forceinline__ bf16x8 pack8(f32x4 a, f32x4 b) {
  bf16x8 r;
  r[0] = (__bf16)a[0]; r[1] = (__bf16)a[1]; r[2] = (__bf16)a[2]; r[3] = (__bf16)a[3];
  r[4] = (__bf16)b[0]; r[5] = (__bf16)b[1]; r[6] = (__bf16)b[2]; r[7] = (__bf16)b[3];
  return r;
}

// ---------------------------------------------------------------------------
__global__ void mask_kernel(const int* __restrict__ mask, float* __restrict__ mb) {
  int i = blockIdx.x * 256 + threadIdx.x;
  if (i < 8 * 2048) mb[i] = (mask[i] != 0) ? 0.0f : -1.0e30f;
}

// ---------------------------------------------------------------------------
// Projection: 768 blocks (3 proj x 256 row-groups of 64); 4 warps x 16 rows.
// W staged in 4 quarters of 32 KB (k-chunk XOR swizzle) -> 4 blocks/CU.
//  QF/KF fragment-major (x32 frags), VF x32 fragment-major (r7 layout).
// ---------------------------------------------------------------------------
__global__ __launch_bounds__(256, 4) void proj_kernel(
    const float* __restrict__ A, const float* __restrict__ Bm,
    const float* __restrict__ Wq, const float* __restrict__ bq,
    const float* __restrict__ Wk, const float* __restrict__ bk,
    const float* __restrict__ Wv, const float* __restrict__ bv,
    __bf16* __restrict__ QF, __bf16* __restrict__ KF, __bf16* __restrict__ VF) {
  __shared__ __bf16 Wl[256 * 64];  // 32 KB: quarter of W (k-quarter), swizzled
  const int pid = blockIdx.x;
  const int proj = pid >> 8;        // 0:Q 1:K 2:V
  const int rb = (pid & 255) << 6;  // row base in flattened [16384]
  const float* __restrict__ X = (proj == 0) ? A : Bm;
  const float* __restrict__ W = (proj == 0) ? Wq : (proj == 1 ? Wk : Wv);
  const float* __restrict__ bias = (proj == 0) ? bq : (proj == 1 ? bk : bv);
  const int tid = threadIdx.x;
  const int w = tid >> 6, l = tid & 63, lo = l & 15, g = l >> 4;
  const int r0 = rb + w * 16;

  f32x4 acc[16];
#pragma unroll
  for (int j = 0; j < 16; ++j) acc[j] = (f32x4){0.f, 0.f, 0.f, 0.f};

  for (int qtr = 0; qtr < 4; ++qtr) {
    if (qtr) __syncthreads();  // all warps done reading previous quarter
    for (int c = tid; c < 2048; c += 256) {
      int n = c >> 3;
      int k8 = (c & 7) << 3;
      const float* wp = &W[n * 256 + qtr * 64 + k8];
      f32x4 w0 = *(const f32x4*)wp;
      f32x4 w1 = *(const f32x4*)(wp + 4);
      int kx = k8 ^ ((n & 7) << 3);  // 8-elem-chunk XOR swizzle (within 64)
      *(bf16x8*)&Wl[n * 64 + kx] = pack8(w0, w1);
    }
    __syncthreads();
#pragma unroll
    for (int ks2 = 0; ks2 < 2; ++ks2) {
      const int kg = qtr * 64 + ks2 * 32 + g * 8;
      const float* xp = &X[(r0 + lo) * 256 + kg];
      bf16x8 xf = pack8(*(const f32x4*)xp, *(const f32x4*)(xp + 4));
#pragma unroll
      for (int nt = 0; nt < 16; ++nt) {
        int n = nt * 16 + lo;
        int kchunk = (ks2 * 4 + g) ^ (n & 7);
        bf16x8 wf = *(const bf16x8*)&Wl[n * 64 + kchunk * 8];
        if (proj == 2) {  // V: D = W * X^T -> V^T[h][row]
          acc[nt] = MFMA16(wf, xf, acc[nt]);
        } else {  // Q/K: D = X * W^T -> out[row][n]
          acc[nt] = MFMA16(xf, wf, acc[nt]);
        }
      }
    }
  }

  if (proj != 2) {
    // fragment-major: idx = (R>>4)*4096 + (h>>5)*512 + ((h>>3)&3)*128
    //                       + (R&15)*8 + (h&7)
    const float cs = (proj == 0) ? 0.090168440f : 1.0f;  // log2(e)/16
    __bf16* __restrict__ O = (proj == 0) ? QF : KF;
    const size_t rgbase = (size_t)(r0 >> 4) << 12;
#pragma unroll
    for (int nt = 0; nt < 16; ++nt) {
      int h = nt * 16 + lo;
      float bb = bias[h];
      size_t hpart = (size_t)((h >> 5) << 9) + (((h >> 3) & 3) << 7) + (h & 7);
#pragma unroll
      for (int r = 0; r < 4; ++r) {
        int R = r0 + g * 4 + r;  // C-layout row
        O[rgbase + hpart + ((R & 15) << 3)] = (__bf16)((acc[nt][r] + bb) * cs);
      }
    }
  } else {
    // V x32 fragment-major: idx = (n>>6)*16384 + (h>>4)*1024 + ((n>>3)&7)*128
    //                             + (h&15)*8 + (n&7)
    const int bidx = r0 >> 11;
    const int nb = r0 & 2047;
    __bf16* __restrict__ Vo = VF + (size_t)bidx * 524288;
#pragma unroll
    for (int ht = 0; ht < 16; ++ht)
#pragma unroll
      for (int r = 0; r < 4; ++r) {
        int h = ht * 16 + g * 4 + r;  // C-layout row = h
        int n = nb + lo;              // C-layout col = kv
        Vo[((size_t)(n >> 6) << 14) + ((h >> 4) << 10) + (((n >> 3) & 7) << 7) +
           ((h & 15) << 3) + (n & 7)] = (__bf16)(acc[ht][r] + bias[h]);
      }
  }
}

// ---------------------------------------------------------------------------
// Attention: grid = 8 b x 16 qt x S; 4 warps x 32 q-rows (QBLK=128).
// KVBLK=32: K/V tiles 16KB each, double-buffered + P (10KB) + mbl (2KB)
// = 77.8KB LDS -> 2 independent blocks/CU. Counted-vmcnt split-phase
// staging: vmcnt(4) before each raw s_barrier, never drained in-loop.
// ---------------------------------------------------------------------------
__global__ __launch_bounds__(256, 2) void attn_kernel(
    const __bf16* __restrict__ QF, const __bf16* __restrict__ KF,
    const __bf16* __restrict__ VF, const float* __restrict__ mb,
    __bf16* __restrict__ Opart, float* __restrict__ mpart,
    float* __restrict__ lpart, float* __restrict__ out,
    int chunk, int direct) {
  extern __shared__ char smem[];  // [K 2x16K][V 2x16K][P 4x2560][mbl 2K]
  const int bid = blockIdx.x;
  const int b = bid & 7;            // batch -> XCD pinning
  const int rest = bid >> 3;
  const int qt = rest & 15;
  const int s = rest >> 4;
  const int tid = threadIdx.x;
  const int w = tid >> 6, l = tid & 63, lo = l & 15, g = l >> 4;
  const int q0 = qt * 128 + w * 32;
  const __bf16* __restrict__ Qb = QF + ((size_t)b * 2048 + q0) * 256;
  const __bf16* __restrict__ Kb = KF + (size_t)b * 2048 * 256;
  const __bf16* __restrict__ Vb = VF + (size_t)b * 524288;
  const float* __restrict__ mbb = mb + b * 2048;
  __bf16* Pw = (__bf16*)(smem + 65536) + w * 1280;  // stride-40 rows
  float* mbl = (float*)(smem + 75776);              // chunk<=512 floats

  bf16x8 qf[2][8];  // 2 q-row-tiles, x32 B-operand frags
#pragma unroll
  for (int u = 0; u < 2; ++u)
#pragma unroll
    for (int hs = 0; hs < 8; ++hs)
      qf[u][hs] = *(const bf16x8*)&Qb[u * 4096 + hs * 512 + l * 8];

  f32x4 oacc[2][16];
#pragma unroll
  for (int u = 0; u < 2; ++u)
#pragma unroll
    for (int i = 0; i < 16; ++i) oacc[u][i] = (f32x4){0.f, 0.f, 0.f, 0.f};
  float m[2] = {-3.0e28f, -3.0e28f}, lsum[2] = {0.f, 0.f};

  const int kv0 = s * chunk;
  const int niter = chunk >> 5;

  // K-half stage: warp w copies 4KB of the 16KB K tile (4 gload16).
  #define STAGE_K(kvb, buf)                                                   \
    {                                                                         \
      const char* gk = (const char*)(Kb + (size_t)(kvb) * 256) + w * 4096 +   \
                       l * 16;                                                \
      char* lk = smem + (buf)*16384 + w * 4096;                               \
      gload16(gk, lk);                                                        \
      gload16(gk + 1024, lk + 1024);                                          \
      gload16(gk + 2048, lk + 2048);                                          \
      gload16(gk + 3072, lk + 3072);                                          \
    }
  // V-half stage: warp w copies ht rows 4w..4w+3 (4 gload16).
  #define STAGE_V(kvb, buf)                                                   \
    {                                                                         \
      const char* gv = (const char*)(Vb + (((size_t)(kvb) >> 6) << 14) +      \
                                     (((kvb) >> 5) & 1) * 512) +              \
                       w * 8192 + l * 16;                                     \
      char* lv = smem + 32768 + (buf)*16384 + w * 4096;                       \
      gload16(gv, lv);                                                        \
      gload16(gv + 2048, lv + 1024);                                          \
      gload16(gv + 4096, lv + 2048);                                          \
      gload16(gv + 6144, lv + 3072);                                          \
    }

  // prologue: mask bias -> LDS; stage tile 0; full drain once.
  if (!direct)
    for (int j = tid; j < chunk; j += 256) mbl[j] = mbb[kv0 + j];
  STAGE_K(kv0, 0);
  STAGE_V(kv0, 0);
  __syncthreads();  // drains vmcnt+lgkm once (prologue only)

  for (int it = 0; it < niter; ++it) {
    const int kvb = kv0 + (it << 5);
    const int cur = it & 1;
    const bool pre = (it + 1 < niter);
    if (pre) STAGE_K(kvb + 32, cur ^ 1);  // K prefetch: lands during QK^T+sm
    const char* kbase = smem + cur * 16384;
    const char* vbase = smem + 32768 + cur * 16384;

    // QK^T: each K frag feeds both q-tiles
    f32x4 sacc[2][2];
#pragma unroll
    for (int u = 0; u < 2; ++u)
#pragma unroll
      for (int t = 0; t < 2; ++t) sacc[u][t] = (f32x4){0.f, 0.f, 0.f, 0.f};
    __builtin_amdgcn_s_setprio(1);
#pragma unroll
    for (int t = 0; t < 2; ++t)
#pragma unroll
      for (int hs = 0; hs < 8; ++hs) {
        bf16x8 kf = *(const bf16x8*)(kbase + t * 8192 + hs * 1024 + l * 16);
        sacc[0][t] = MFMA16(kf, qf[0][hs], sacc[0][t]);
        sacc[1][t] = MFMA16(kf, qf[1][hs], sacc[1][t]);
      }
    __builtin_amdgcn_s_setprio(0);

    // mask bias + per-tile online softmax
    f32x4 bias4[2];
#pragma unroll
    for (int t = 0; t < 2; ++t) {
      if (direct)
        bias4[t] = *(const f32x4*)&mbb[kvb + t * 16 + g * 4];
      else
        bias4[t] = *(const f32x4*)&mbl[(it << 5) + t * 16 + g * 4];
    }
#pragma unroll
    for (int u = 0; u < 2; ++u) {
      float tmax = -3.4e38f;
#pragma unroll
      for (int t = 0; t < 2; ++t)
#pragma unroll
        for (int r = 0; r < 4; ++r) {
          sacc[u][t][r] += bias4[t][r];
          tmax = fmaxf(tmax, sacc[u][t][r]);
        }
      tmax = fmaxf(tmax, __shfl_xor(tmax, 16));
      tmax = fmaxf(tmax, __shfl_xor(tmax, 32));
      if (!__all(tmax <= m[u] + 8.0f)) {  // defer-max rescale
        float mn = fmaxf(m[u], tmax);
        float f = EXP2(m[u] - mn);
        lsum[u] *= f;
#pragma unroll
        for (int i = 0; i < 16; ++i) {
          oacc[u][i][0] *= f; oacc[u][i][1] *= f;
          oacc[u][i][2] *= f; oacc[u][i][3] *= f;
        }
        m[u] = mn;
      }
#pragma unroll
      for (int t = 0; t < 2; ++t) {
        float p0 = EXP2(sacc[u][t][0] - m[u]);
        float p1 = EXP2(sacc[u][t][1] - m[u]);
        float p2 = EXP2(sacc[u][t][2] - m[u]);
        float p3 = EXP2(sacc[u][t][3] - m[u]);
        lsum[u] += (p0 + p1) + (p2 + p3);
        bf16x4 pk;
        pk[0] = (__bf16)p0; pk[1] = (__bf16)p1;
        pk[2] = (__bf16)p2; pk[3] = (__bf16)p3;
        *(bf16x4*)&Pw[u * 640 + lo * 40 + t * 16 + g * 4] = pk;
      }
    }
    // P frags (same-wave LDS write->read)
    bf16x8 pf[2];
#pragma unroll
    for (int u = 0; u < 2; ++u)
      pf[u] = *(const bf16x8*)&Pw[u * 640 + lo * 40 + g * 8];

    // (A) V(i) retired (K(i+1) stays in flight); publish V(i) to all warps.
    if (direct || !pre) {
      asm volatile("s_waitcnt vmcnt(0)" ::: "memory");
    } else {
      asm volatile("s_waitcnt vmcnt(4)" ::: "memory");
    }
    __builtin_amdgcn_s_barrier();
    __builtin_amdgcn_sched_barrier(0);

    if (pre) STAGE_V(kvb + 32, cur ^ 1);  // V prefetch: lands during PV+QK^T

    // PV: each V frag feeds both q-tiles
    __builtin_amdgcn_s_setprio(1);
#pragma unroll
    for (int ht = 0; ht < 16; ++ht) {
      bf16x8 vf = *(const bf16x8*)(vbase + ht * 1024 + l * 16);
      oacc[0][ht] = MFMA16(vf, pf[0], oacc[0][ht]);
      oacc[1][ht] = MFMA16(vf, pf[1], oacc[1][ht]);
    }
    __builtin_amdgcn_s_setprio(0);

    // (B) K(i+1) retired (V(i+1) stays in flight); publish K(i+1).
    if (direct || !pre) {
      asm volatile("s_waitcnt vmcnt(0)" ::: "memory");
    } else {
      asm volatile("s_waitcnt vmcnt(4)" ::: "memory");
    }
    __builtin_amdgcn_s_barrier();
    __builtin_amdgcn_sched_barrier(0);
  }

#pragma unroll
  for (int u = 0; u < 2; ++u) {
    float ls = lsum[u];
    ls += __shfl_xor(ls, 16);
    ls += __shfl_xor(ls, 32);
    const int q0u = q0 + u * 16;
    if (direct) {
      float inv = 1.0f / ls;
      float* __restrict__ Ob = out + ((size_t)b * 2048 + q0u) * 256;
#pragma unroll
      for (int ht = 0; ht < 16; ++ht) {
        f32x4 v = oacc[u][ht];
        v[0] *= inv; v[1] *= inv; v[2] *= inv; v[3] *= inv;
        *(f32x4*)&Ob[lo * 256 + ht * 16 + g * 4] = v;
      }
    } else {
      const size_t rowbase = (size_t)(s * 8 + b) * 2048 + q0u;
      __bf16* __restrict__ Ob = Opart + rowbase * 256;
#pragma unroll
      for (int ht = 0; ht < 16; ++ht) {
        f32x4 v = oacc[u][ht];
        bf16x4 pk;
        pk[0] = (__bf16)v[0]; pk[1] = (__bf16)v[1];
        pk[2] = (__bf16)v[2]; pk[3] = (__bf16)v[3];
        *(bf16x4*)&Ob[lo * 256 + ht * 16 + g * 4] = pk;
      }
      if (l < 16) {
        mpart[rowbase + lo] = m[u];
        lpart[rowbase + lo] = ls;
      }
    }
  }
}

// ---------------------------------------------------------------------------
// Combine: out[row][h] = sum_s 2^(m_s-M) O_s[row][h] / sum_s 2^(m_s-M) l_s
// Opart is bf16 (8B coalesced loads per thread per split).
// ---------------------------------------------------------------------------
__global__ __launch_bounds__(256) void combine_kernel(
    const __bf16* __restrict__ Opart, const float* __restrict__ mpart,
    const float* __restrict__ lpart, float* __restrict__ out, int nsplit) {
  int t = blockIdx.x * 256 + threadIdx.x;
  int row = t >> 6;
  int h4 = (t & 63) << 2;
  float M = -3.4e38f;
  for (int s = 0; s < nsplit; ++s) M = fmaxf(M, mpart[s * 16384 + row]);
  f32x4 acc = (f32x4){0.f, 0.f, 0.f, 0.f};
  float denom = 0.f;
  for (int s = 0; s < nsplit; ++s) {
    float wgt = EXP2(mpart[s * 16384 + row] - M);
    denom += wgt * lpart[s * 16384 + row];
    bf16x4 o = *(const bf16x4*)&Opart[((size_t)s * 16384 + row) * 256 + h4];
    acc[0] += wgt * (float)o[0]; acc[1] += wgt * (float)o[1];
    acc[2] += wgt * (float)o[2]; acc[3] += wgt * (float)o[3];
  }
  float inv = 1.0f / denom;
  f32x4 r;
  r[0] = acc[0] * inv; r[1] = acc[1] * inv;
  r[2] = acc[2] * inv; r[3] = acc[3] * inv;
  *(f32x4*)&out[(size_t)row * 256 + h4] = r;
}

// ---------------------------------------------------------------------------
extern "C" void kernel_launch(void* const* d_in, const int* in_sizes, int n_in,
                              void* d_out, int out_size, void* d_ws, size_t ws_size,
                              hipStream_t stream) {
  const float* A = (const float*)d_in[0];
  const float* B = (const float*)d_in[1];
  const int* mask = (const int*)d_in[2];
  const float* Wq = (const float*)d_in[3];
  const float* bq = (const float*)d_in[4];
  const float* Wk = (const float*)d_in[5];
  const float* bk = (const float*)d_in[6];
  const float* Wv = (const float*)d_in[7];
  const float* bv = (const float*)d_in[8];

  char* ws = (char*)d_ws;
  __bf16* QF = (__bf16*)(ws);                         // 8 MB
  __bf16* KF = (__bf16*)(ws + (8ull << 20));          // 8 MB
  __bf16* VF = (__bf16*)(ws + (16ull << 20));         // 8 MB
  float* mb = (float*)(ws + (24ull << 20));           // 64 KB
  float* mpart = (float*)(ws + (24ull << 20) + 0x10000);   // <=256 KB
  float* lpart = (float*)(ws + (24ull << 20) + 0x60000);   // <=256 KB
  __bf16* Opart = (__bf16*)(ws + (25ull << 20));           // S * 8 MB (bf16)

  const size_t base = 25ull << 20;
  const size_t part = 8ull << 20;
  int S;
  if (ws_size >= base + 4 * part) S = 4;
  else if (ws_size >= base + 2 * part) S = 2;
  else if (ws_size >= base + 1 * part) S = 1;
  else S = 0;  // direct mode (no split)

  const int SMEM = 65536 + 4 * 1280 * 2 + 2048;  // 77824 B -> 2 blocks/CU
  (void)hipFuncSetAttribute((const void*)attn_kernel,
                            hipFuncAttributeMaxDynamicSharedMemorySize, SMEM);

  mask_kernel<<<64, 256, 0, stream>>>(mask, mb);
  proj_kernel<<<768, 256, 0, stream>>>(A, B, Wq, bq, Wk, bk, Wv, bv, QF, KF, VF);
  if (S == 0) {
    attn_kernel<<<128, 256, SMEM, stream>>>(QF, KF, VF, mb, nullptr, nullptr,
                                            nullptr, (float*)d_out, 2048, 1);
  } else {
    attn_kernel<<<128 * S, 256, SMEM, stream>>>(QF, KF, VF, mb, Opart, mpart,
                                                lpart, nullptr, 2048 / S, 0);
    combine_kernel<<<4096, 256, 0, stream>>>(Opart, mpart, lpart,
                                             (float*)d_out, S);
  }
}

// Round 10
// 93.175 us; speedup vs baseline: 1.2867x; 1.1025x over previous
//
#include <hip/hip_runtime.h>

// ---------------------------------------------------------------------------
// CrossGraphNodeAttention: out = softmax(mask(Q K^T / 16)) V per batch
//   Q = A@Wq^T+bq, K = B@Wk^T+bk, V = B@Wv^T+bv;  B=8, N=2048, H=256
// Round 10: proj overhaul. wprep converts W -> bf16 pre-swizzled fragment
// layout once (+ folds Q scale, + mask bias). proj v2 stages W quarters via
// global_load_lds (dbuf 2x32KB), X in registers, 1 barrier/quarter.
// attn unchanged from r9 (52 us, verified).
// ---------------------------------------------------------------------------

typedef __attribute__((ext_vector_type(8))) __bf16 bf16x8;
typedef __attribute__((ext_vector_type(4))) __bf16 bf16x4;
typedef __attribute__((ext_vector_type(4))) float f32x4;

#if __has_builtin(__builtin_amdgcn_exp2f)
#define EXP2(x) __builtin_amdgcn_exp2f(x)
#else
#define EXP2(x) exp2f(x)
#endif

#define MFMA16(a, b, c) __builtin_amdgcn_mfma_f32_16x16x32_bf16((a), (b), (c), 0, 0, 0)

typedef const __attribute__((address_space(1))) char gas_char;
typedef __attribute__((address_space(3))) char las_char;

// global -> LDS direct copy: 16B/lane, LDS dest = uniform base (+lane*16 HW).
static __device__ __forceinline__ void gload16(const void* g, void* l) {
  __builtin_amdgcn_global_load_lds((gas_char*)g, (las_char*)l, 16, 0, 0);
}

static __device__ __forceinline__ bf16x8 pack8(f32x4 a, f32x4 b) {
  bf16x8 r;
  r[0] = (__bf16)a[0]; r[1] = (__bf16)a[1]; r[2] = (__bf16)a[2]; r[3] = (__bf16)a[3];
  r[4] = (__bf16)b[0]; r[5] = (__bf16)b[1]; r[6] = (__bf16)b[2]; r[7] = (__bf16)b[3];
  return r;
}

// ---------------------------------------------------------------------------
// wprep: blocks 0..95 convert W (f32 -> bf16, pre-swizzled quarter layout,
// Wq scaled by log2e/16); blocks 96..159 build the mask bias.
//   Wb[w][qtr][n*64 + (k8 ^ ((n&7)*8))] = W[n][qtr*64 + k8]
// ---------------------------------------------------------------------------
__global__ __launch_bounds__(256) void wprep_kernel(
    const float* __restrict__ Wq, const float* __restrict__ Wk,
    const float* __restrict__ Wv, const int* __restrict__ mask,
    __bf16* __restrict__ Wb, float* __restrict__ mb) {
  const int bid = blockIdx.x;
  if (bid < 96) {
    int c = bid * 256 + threadIdx.x;  // chunk id, 8192 chunks per W
    int w_id = c >> 13;
    int j = c & 8191;
    const float* __restrict__ W = (w_id == 0) ? Wq : (w_id == 1 ? Wk : Wv);
    int n = j >> 5;
    int c5 = j & 31;
    int qtr = c5 >> 3;
    int k8 = (c5 & 7) << 3;
    const float* wp = &W[n * 256 + qtr * 64 + k8];
    f32x4 w0 = *(const f32x4*)wp;
    f32x4 w1 = *(const f32x4*)(wp + 4);
    if (w_id == 0) {
      const float cs = 0.090168440f;  // log2(e)/16
      w0[0] *= cs; w0[1] *= cs; w0[2] *= cs; w0[3] *= cs;
      w1[0] *= cs; w1[1] *= cs; w1[2] *= cs; w1[3] *= cs;
    }
    int kx = k8 ^ ((n & 7) << 3);
    *(bf16x8*)&Wb[(size_t)w_id * 65536 + qtr * 16384 + n * 64 + kx] =
        pack8(w0, w1);
  } else {
    int i = (bid - 96) * 256 + threadIdx.x;
    if (i < 8 * 2048) mb[i] = (mask[i] != 0) ? 0.0f : -1.0e30f;
  }
}

// ---------------------------------------------------------------------------
// Projection v2: 768 blocks (3 proj x 256 row-groups of 64); 4 warps x 16
// rows. X in registers (prologue); W quarters gload16-staged, double-buffered
// (2x32KB LDS), 1 barrier per quarter. Epilogue layouts identical to r9.
// ---------------------------------------------------------------------------
__global__ __launch_bounds__(256, 2) void proj_kernel(
    const float* __restrict__ A, const float* __restrict__ Bm,
    const __bf16* __restrict__ Wb,
    const float* __restrict__ bq, const float* __restrict__ bk,
    const float* __restrict__ bv,
    __bf16* __restrict__ QF, __bf16* __restrict__ KF, __bf16* __restrict__ VF) {
  extern __shared__ char smem[];  // 2 x 32KB W quarter buffers
  const int pid = blockIdx.x;
  const int proj = pid >> 8;        // 0:Q 1:K 2:V
  const int rb = (pid & 255) << 6;  // row base in flattened [16384]
  const float* __restrict__ X = (proj == 0) ? A : Bm;
  const char* __restrict__ Wbp = (const char*)(Wb + (size_t)proj * 65536);
  const float* __restrict__ bias = (proj == 0) ? bq : (proj == 1 ? bk : bv);
  const int tid = threadIdx.x;
  const int w = tid >> 6, l = tid & 63, lo = l & 15, g = l >> 4;
  const int r0 = rb + w * 16;

  // X prologue: 8 chunks (qtr*2+ks2), 32B f32 each -> bf16x8 regs
  bf16x8 xf[8];
#pragma unroll
  for (int q8 = 0; q8 < 8; ++q8) {
    const float* xp = &X[(r0 + lo) * 256 + q8 * 32 + g * 8];
    xf[q8] = pack8(*(const f32x4*)xp, *(const f32x4*)(xp + 4));
  }

  f32x4 acc[16];
#pragma unroll
  for (int j = 0; j < 16; ++j) acc[j] = (f32x4){0.f, 0.f, 0.f, 0.f};

  // stage quarter qtr into buffer buf: 32 wave-chunks of 1KB; warp w takes
  // chunks j*4+w (j=0..7).
  #define STAGEW(qtr, buf)                                                    \
    {                                                                         \
      const char* gw = Wbp + (qtr)*32768 + w * 1024 + l * 16;                 \
      char* lw = smem + (buf)*32768 + w * 1024;                               \
      gload16(gw, lw);                                                        \
      gload16(gw + 4096, lw + 4096);                                          \
      gload16(gw + 8192, lw + 8192);                                          \
      gload16(gw + 12288, lw + 12288);                                        \
      gload16(gw + 16384, lw + 16384);                                        \
      gload16(gw + 20480, lw + 20480);                                        \
      gload16(gw + 24576, lw + 24576);                                        \
      gload16(gw + 28672, lw + 28672);                                        \
    }

  STAGEW(0, 0);
  __syncthreads();  // quarter 0 visible

  for (int qtr = 0; qtr < 4; ++qtr) {
    const int cur = qtr & 1;
    if (qtr < 3) STAGEW(qtr + 1, cur ^ 1);  // lands during compute
    const __bf16* Wl = (const __bf16*)(smem + cur * 32768);
#pragma unroll
    for (int ks2 = 0; ks2 < 2; ++ks2) {
      bf16x8 xcur = xf[qtr * 2 + ks2];
#pragma unroll
      for (int nt = 0; nt < 16; ++nt) {
        int n = nt * 16 + lo;
        int kchunk = (ks2 * 4 + g) ^ (n & 7);
        bf16x8 wf = *(const bf16x8*)&Wl[n * 64 + kchunk * 8];
        if (proj == 2) {  // V: D = W * X^T -> V^T[h][row]
          acc[nt] = MFMA16(wf, xcur, acc[nt]);
        } else {  // Q/K: D = X * W^T -> out[row][n]
          acc[nt] = MFMA16(xcur, wf, acc[nt]);
        }
      }
    }
    __syncthreads();  // drains next-stage loads; all warps done with cur
  }

  if (proj != 2) {
    // fragment-major: idx = (R>>4)*4096 + (h>>5)*512 + ((h>>3)&3)*128
    //                       + (R&15)*8 + (h&7)
    const float cs = (proj == 0) ? 0.090168440f : 1.0f;  // bias scale (W pre-scaled)
    __bf16* __restrict__ O = (proj == 0) ? QF : KF;
    const size_t rgbase = (size_t)(r0 >> 4) << 12;
#pragma unroll
    for (int nt = 0; nt < 16; ++nt) {
      int h = nt * 16 + lo;
      float bb = bias[h] * cs;
      size_t hpart = (size_t)((h >> 5) << 9) + (((h >> 3) & 3) << 7) + (h & 7);
#pragma unroll
      for (int r = 0; r < 4; ++r) {
        int R = r0 + g * 4 + r;  // C-layout row
        O[rgbase + hpart + ((R & 15) << 3)] = (__bf16)(acc[nt][r] + bb);
      }
    }
  } else {
    // V x32 fragment-major: idx = (n>>6)*16384 + (h>>4)*1024 + ((n>>3)&7)*128
    //                             + (h&15)*8 + (n&7)
    const int bidx = r0 >> 11;
    const int nb = r0 & 2047;
    __bf16* __restrict__ Vo = VF + (size_t)bidx * 524288;
#pragma unroll
    for (int ht = 0; ht < 16; ++ht)
#pragma unroll
      for (int r = 0; r < 4; ++r) {
        int h = ht * 16 + g * 4 + r;  // C-layout row = h
        int n = nb + lo;              // C-layout col = kv
        Vo[((size_t)(n >> 6) << 14) + ((h >> 4) << 10) + (((n >> 3) & 7) << 7) +
           ((h & 15) << 3) + (n & 7)] = (__bf16)(acc[ht][r] + bias[h]);
      }
  }
}

// ---------------------------------------------------------------------------
// Attention (unchanged from r9): QBLK=128, KVBLK=32, 2 blocks/CU, counted
// vmcnt split-phase staging, bf16 Opart.
// ---------------------------------------------------------------------------
__global__ __launch_bounds__(256, 2) void attn_kernel(
    const __bf16* __restrict__ QF, const __bf16* __restrict__ KF,
    const __bf16* __restrict__ VF, const float* __restrict__ mb,
    __bf16* __restrict__ Opart, float* __restrict__ mpart,
    float* __restrict__ lpart, float* __restrict__ out,
    int chunk, int direct) {
  extern __shared__ char smem[];  // [K 2x16K][V 2x16K][P 4x2560][mbl 2K]
  const int bid = blockIdx.x;
  const int b = bid & 7;            // batch -> XCD pinning
  const int rest = bid >> 3;
  const int qt = rest & 15;
  const int s = rest >> 4;
  const int tid = threadIdx.x;
  const int w = tid >> 6, l = tid & 63, lo = l & 15, g = l >> 4;
  const int q0 = qt * 128 + w * 32;
  const __bf16* __restrict__ Qb = QF + ((size_t)b * 2048 + q0) * 256;
  const __bf16* __restrict__ Kb = KF + (size_t)b * 2048 * 256;
  const __bf16* __restrict__ Vb = VF + (size_t)b * 524288;
  const float* __restrict__ mbb = mb + b * 2048;
  __bf16* Pw = (__bf16*)(smem + 65536) + w * 1280;  // stride-40 rows
  float* mbl = (float*)(smem + 75776);              // chunk<=512 floats

  bf16x8 qf[2][8];  // 2 q-row-tiles, x32 B-operand frags
#pragma unroll
  for (int u = 0; u < 2; ++u)
#pragma unroll
    for (int hs = 0; hs < 8; ++hs)
      qf[u][hs] = *(const bf16x8*)&Qb[u * 4096 + hs * 512 + l * 8];

  f32x4 oacc[2][16];
#pragma unroll
  for (int u = 0; u < 2; ++u)
#pragma unroll
    for (int i = 0; i < 16; ++i) oacc[u][i] = (f32x4){0.f, 0.f, 0.f, 0.f};
  float m[2] = {-3.0e28f, -3.0e28f}, lsum[2] = {0.f, 0.f};

  const int kv0 = s * chunk;
  const int niter = chunk >> 5;

  #define STAGE_K(kvb, buf)                                                   \
    {                                                                         \
      const char* gk = (const char*)(Kb + (size_t)(kvb) * 256) + w * 4096 +   \
                       l * 16;                                                \
      char* lk = smem + (buf)*16384 + w * 4096;                               \
      gload16(gk, lk);                                                        \
      gload16(gk + 1024, lk + 1024);                                          \
      gload16(gk + 2048, lk + 2048);                                          \
      gload16(gk + 3072, lk + 3072);                                          \
    }
  #define STAGE_V(kvb, buf)                                                   \
    {                                                                         \
      const char* gv = (const char*)(Vb + (((size_t)(kvb) >> 6) << 14) +      \
                                     (((kvb) >> 5) & 1) * 512) +              \
                       w * 8192 + l * 16;                                     \
      char* lv = smem + 32768 + (buf)*16384 + w * 4096;                       \
      gload16(gv, lv);                                                        \
      gload16(gv + 2048, lv + 1024);                                          \
      gload16(gv + 4096, lv + 2048);                                          \
      gload16(gv + 6144, lv + 3072);                                          \
    }

  if (!direct)
    for (int j = tid; j < chunk; j += 256) mbl[j] = mbb[kv0 + j];
  STAGE_K(kv0, 0);
  STAGE_V(kv0, 0);
  __syncthreads();  // full drain (prologue only)

  for (int it = 0; it < niter; ++it) {
    const int kvb = kv0 + (it << 5);
    const int cur = it & 1;
    const bool pre = (it + 1 < niter);
    if (pre) STAGE_K(kvb + 32, cur ^ 1);
    const char* kbase = smem + cur * 16384;
    const char* vbase = smem + 32768 + cur * 16384;

    f32x4 sacc[2][2];
#pragma unroll
    for (int u = 0; u < 2; ++u)
#pragma unroll
      for (int t = 0; t < 2; ++t) sacc[u][t] = (f32x4){0.f, 0.f, 0.f, 0.f};
    __builtin_amdgcn_s_setprio(1);
#pragma unroll
    for (int t = 0; t < 2; ++t)
#pragma unroll
      for (int hs = 0; hs < 8; ++hs) {
        bf16x8 kf = *(const bf16x8*)(kbase + t * 8192 + hs * 1024 + l * 16);
        sacc[0][t] = MFMA16(kf, qf[0][hs], sacc[0][t]);
        sacc[1][t] = MFMA16(kf, qf[1][hs], sacc[1][t]);
      }
    __builtin_amdgcn_s_setprio(0);

    f32x4 bias4[2];
#pragma unroll
    for (int t = 0; t < 2; ++t) {
      if (direct)
        bias4[t] = *(const f32x4*)&mbb[kvb + t * 16 + g * 4];
      else
        bias4[t] = *(const f32x4*)&mbl[(it << 5) + t * 16 + g * 4];
    }
#pragma unroll
    for (int u = 0; u < 2; ++u) {
      float tmax = -3.4e38f;
#pragma unroll
      for (int t = 0; t < 2; ++t)
#pragma unroll
        for (int r = 0; r < 4; ++r) {
          sacc[u][t][r] += bias4[t][r];
          tmax = fmaxf(tmax, sacc[u][t][r]);
        }
      tmax = fmaxf(tmax, __shfl_xor(tmax, 16));
      tmax = fmaxf(tmax, __shfl_xor(tmax, 32));
      if (!__all(tmax <= m[u] + 8.0f)) {  // defer-max rescale
        float mn = fmaxf(m[u], tmax);
        float f = EXP2(m[u] - mn);
        lsum[u] *= f;
#pragma unroll
        for (int i = 0; i < 16; ++i) {
          oacc[u][i][0] *= f; oacc[u][i][1] *= f;
          oacc[u][i][2] *= f; oacc[u][i][3] *= f;
        }
        m[u] = mn;
      }
#pragma unroll
      for (int t = 0; t < 2; ++t) {
        float p0 = EXP2(sacc[u][t][0] - m[u]);
        float p1 = EXP2(sacc[u][t][1] - m[u]);
        float p2 = EXP2(sacc[u][t][2] - m[u]);
        float p3 = EXP2(sacc[u][t][3] - m[u]);
        lsum[u] += (p0 + p1) + (p2 + p3);
        bf16x4 pk;
        pk[0] = (__bf16)p0; pk[1] = (__bf16)p1;
        pk[2] = (__bf16)p2; pk[3] = (__bf16)p3;
        *(bf16x4*)&Pw[u * 640 + lo * 40 + t * 16 + g * 4] = pk;
      }
    }
    bf16x8 pf[2];
#pragma unroll
    for (int u = 0; u < 2; ++u)
      pf[u] = *(const bf16x8*)&Pw[u * 640 + lo * 40 + g * 8];

    if (direct || !pre) {
      asm volatile("s_waitcnt vmcnt(0)" ::: "memory");
    } else {
      asm volatile("s_waitcnt vmcnt(4)" ::: "memory");
    }
    __builtin_amdgcn_s_barrier();
    __builtin_amdgcn_sched_barrier(0);

    if (pre) STAGE_V(kvb + 32, cur ^ 1);

    __builtin_amdgcn_s_setprio(1);
#pragma unroll
    for (int ht = 0; ht < 16; ++ht) {
      bf16x8 vf = *(const bf16x8*)(vbase + ht * 1024 + l * 16);
      oacc[0][ht] = MFMA16(vf, pf[0], oacc[0][ht]);
      oacc[1][ht] = MFMA16(vf, pf[1], oacc[1][ht]);
    }
    __builtin_amdgcn_s_setprio(0);

    if (direct || !pre) {
      asm volatile("s_waitcnt vmcnt(0)" ::: "memory");
    } else {
      asm volatile("s_waitcnt vmcnt(4)" ::: "memory");
    }
    __builtin_amdgcn_s_barrier();
    __builtin_amdgcn_sched_barrier(0);
  }

#pragma unroll
  for (int u = 0; u < 2; ++u) {
    float ls = lsum[u];
    ls += __shfl_xor(ls, 16);
    ls += __shfl_xor(ls, 32);
    const int q0u = q0 + u * 16;
    if (direct) {
      float inv = 1.0f / ls;
      float* __restrict__ Ob = out + ((size_t)b * 2048 + q0u) * 256;
#pragma unroll
      for (int ht = 0; ht < 16; ++ht) {
        f32x4 v = oacc[u][ht];
        v[0] *= inv; v[1] *= inv; v[2] *= inv; v[3] *= inv;
        *(f32x4*)&Ob[lo * 256 + ht * 16 + g * 4] = v;
      }
    } else {
      const size_t rowbase = (size_t)(s * 8 + b) * 2048 + q0u;
      __bf16* __restrict__ Ob = Opart + rowbase * 256;
#pragma unroll
      for (int ht = 0; ht < 16; ++ht) {
        f32x4 v = oacc[u][ht];
        bf16x4 pk;
        pk[0] = (__bf16)v[0]; pk[1] = (__bf16)v[1];
        pk[2] = (__bf16)v[2]; pk[3] = (__bf16)v[3];
        *(bf16x4*)&Ob[lo * 256 + ht * 16 + g * 4] = pk;
      }
      if (l < 16) {
        mpart[rowbase + lo] = m[u];
        lpart[rowbase + lo] = ls;
      }
    }
  }
}

// ---------------------------------------------------------------------------
__global__ __launch_bounds__(256) void combine_kernel(
    const __bf16* __restrict__ Opart, const float* __restrict__ mpart,
    const float* __restrict__ lpart, float* __restrict__ out, int nsplit) {
  int t = blockIdx.x * 256 + threadIdx.x;
  int row = t >> 6;
  int h4 = (t & 63) << 2;
  float M = -3.4e38f;
  for (int s = 0; s < nsplit; ++s) M = fmaxf(M, mpart[s * 16384 + row]);
  f32x4 acc = (f32x4){0.f, 0.f, 0.f, 0.f};
  float denom = 0.f;
  for (int s = 0; s < nsplit; ++s) {
    float wgt = EXP2(mpart[s * 16384 + row] - M);
    denom += wgt * lpart[s * 16384 + row];
    bf16x4 o = *(const bf16x4*)&Opart[((size_t)s * 16384 + row) * 256 + h4];
    acc[0] += wgt * (float)o[0]; acc[1] += wgt * (float)o[1];
    acc[2] += wgt * (float)o[2]; acc[3] += wgt * (float)o[3];
  }
  float inv = 1.0f / denom;
  f32x4 r;
  r[0] = acc[0] * inv; r[1] = acc[1] * inv;
  r[2] = acc[2] * inv; r[3] = acc[3] * inv;
  *(f32x4*)&out[(size_t)row * 256 + h4] = r;
}

// ---------------------------------------------------------------------------
extern "C" void kernel_launch(void* const* d_in, const int* in_sizes, int n_in,
                              void* d_out, int out_size, void* d_ws, size_t ws_size,
                              hipStream_t stream) {
  const float* A = (const float*)d_in[0];
  const float* B = (const float*)d_in[1];
  const int* mask = (const int*)d_in[2];
  const float* Wq = (const float*)d_in[3];
  const float* bq = (const float*)d_in[4];
  const float* Wk = (const float*)d_in[5];
  const float* bk = (const float*)d_in[6];
  const float* Wv = (const float*)d_in[7];
  const float* bv = (const float*)d_in[8];

  char* ws = (char*)d_ws;
  __bf16* QF = (__bf16*)(ws);                         // 8 MB
  __bf16* KF = (__bf16*)(ws + (8ull << 20));          // 8 MB
  __bf16* VF = (__bf16*)(ws + (16ull << 20));         // 8 MB
  float* mb = (float*)(ws + (24ull << 20));           // 64 KB
  float* mpart = (float*)(ws + (24ull << 20) + 0x10000);   // <=256 KB
  float* lpart = (float*)(ws + (24ull << 20) + 0x60000);   // <=256 KB
  __bf16* Wb = (__bf16*)(ws + (24ull << 20) + 0xA0000);    // 384 KB
  __bf16* Opart = (__bf16*)(ws + (25ull << 20));           // S * 8 MB (bf16)

  const size_t base = 25ull << 20;
  const size_t part = 8ull << 20;
  int S;
  if (ws_size >= base + 4 * part) S = 4;
  else if (ws_size >= base + 2 * part) S = 2;
  else if (ws_size >= base + 1 * part) S = 1;
  else S = 0;  // direct mode (no split)

  const int PSMEM = 65536;  // proj: 2 x 32KB W quarter dbuf
  (void)hipFuncSetAttribute((const void*)proj_kernel,
                            hipFuncAttributeMaxDynamicSharedMemorySize, PSMEM);
  const int SMEM = 65536 + 4 * 1280 * 2 + 2048;  // 77824 B -> 2 blocks/CU
  (void)hipFuncSetAttribute((const void*)attn_kernel,
                            hipFuncAttributeMaxDynamicSharedMemorySize, SMEM);

  wprep_kernel<<<160, 256, 0, stream>>>(Wq, Wk, Wv, mask, Wb, mb);
  proj_kernel<<<768, 256, PSMEM, stream>>>(A, B, Wb, bq, bk, bv, QF, KF, VF);
  if (S == 0) {
    attn_kernel<<<128, 256, SMEM, stream>>>(QF, KF, VF, mb, nullptr, nullptr,
                                            nullptr, (float*)d_out, 2048, 1);
  } else {
    attn_kernel<<<128 * S, 256, SMEM, stream>>>(QF, KF, VF, mb, Opart, mpart,
                                                lpart, nullptr, 2048 / S, 0);
    combine_kernel<<<4096, 256, 0, stream>>>(Opart, mpart, lpart,
                                             (float*)d_out, S);
  }
}